// Round 1
// baseline (396.362 us; speedup 1.0000x reference)
//
#include <hip/hip_runtime.h>

// Problem constants
// B=2 S=8192 E=1024 H=16 D=64 CHUNK=128 NC=64

using h16   = _Float16;
using h16x8 = __attribute__((ext_vector_type(8))) _Float16;
using h16x4 = __attribute__((ext_vector_type(4))) _Float16;
using f32x4 = __attribute__((ext_vector_type(4))) float;

#define MFMA16(a,b,c) __builtin_amdgcn_mfma_f32_16x16x32_f16(a,b,c,0,0,0)

// ---------------- fp32 -> fp16 convert (8 elems/thread) ----------------
__global__ __launch_bounds__(256) void k_cvt(const float* __restrict__ s,
                                             h16* __restrict__ d, int n) {
  int i = (blockIdx.x * 256 + threadIdx.x) * 8;
  if (i >= n) return;
  float4 a = *(const float4*)(s + i);
  float4 b = *(const float4*)(s + i + 4);
  h16x8 o;
  o[0]=(h16)a.x; o[1]=(h16)a.y; o[2]=(h16)a.z; o[3]=(h16)a.w;
  o[4]=(h16)b.x; o[5]=(h16)b.y; o[6]=(h16)b.z; o[7]=(h16)b.w;
  *(h16x8*)(d + i) = o;
}

// ---------------- QKV GEMM (M=16384, N=3072, K=1024) + RoPE ----------------
// 128x128 tile, 4 waves (2x2 quadrants of 64x64), BK=64, reg-prefetch pipeline.
__global__ __launch_bounds__(256) void k_qkv(
    const h16* __restrict__ xh, const h16* __restrict__ w3,
    const float* __restrict__ fc,
    h16* __restrict__ qh, h16* __restrict__ kh, h16* __restrict__ vh)
{
  __shared__ __align__(16) h16 lA[128*64];
  __shared__ __align__(16) h16 lB[128*64];
  const int tid = threadIdx.x;
  const int m0 = blockIdx.x * 128;
  const int nt = blockIdx.y;
  const int n0 = nt * 128;
  const int w = tid >> 6, l = tid & 63;
  const int wr = w >> 1, wc = w & 1;
  const int sr = tid >> 3, sc = tid & 7;      // staging row (+i*32), 16B slot
  const int ssl = sc ^ (sr & 7);              // XOR-swizzled slot
  const h16* At = xh + (size_t)m0 * 1024;
  const h16* Bt = w3 + (size_t)n0 * 1024;

  f32x4 acc[4][4] = {};
  h16x8 ra[4], rb[4];
  #pragma unroll
  for (int i = 0; i < 4; i++) {
    ra[i] = *(const h16x8*)(At + (size_t)(i*32+sr)*1024 + sc*8);
    rb[i] = *(const h16x8*)(Bt + (size_t)(i*32+sr)*1024 + sc*8);
  }
  #pragma unroll
  for (int i = 0; i < 4; i++) {
    *(h16x8*)(lA + (i*32+sr)*64 + ssl*8) = ra[i];
    *(h16x8*)(lB + (i*32+sr)*64 + ssl*8) = rb[i];
  }
  __syncthreads();

  for (int kt = 0; kt < 16; ++kt) {
    if (kt < 15) {
      #pragma unroll
      for (int i = 0; i < 4; i++) {
        ra[i] = *(const h16x8*)(At + (size_t)(i*32+sr)*1024 + (kt+1)*64 + sc*8);
        rb[i] = *(const h16x8*)(Bt + (size_t)(i*32+sr)*1024 + (kt+1)*64 + sc*8);
      }
    }
    #pragma unroll
    for (int ks = 0; ks < 2; ++ks) {
      h16x8 af[4], bf[4];
      #pragma unroll
      for (int mf = 0; mf < 4; mf++) {
        int row = wr*64 + mf*16 + (l & 15);
        int slot = (ks*4 + (l >> 4)) ^ (row & 7);
        af[mf] = *(const h16x8*)(lA + row*64 + slot*8);
      }
      #pragma unroll
      for (int nf = 0; nf < 4; nf++) {
        int row = wc*64 + nf*16 + (l & 15);
        int slot = (ks*4 + (l >> 4)) ^ (row & 7);
        bf[nf] = *(const h16x8*)(lB + row*64 + slot*8);
      }
      #pragma unroll
      for (int mf = 0; mf < 4; mf++)
        #pragma unroll
        for (int nf = 0; nf < 4; nf++)
          acc[mf][nf] = MFMA16(af[mf], bf[nf], acc[mf][nf]);
    }
    __syncthreads();
    if (kt < 15) {
      #pragma unroll
      for (int i = 0; i < 4; i++) {
        *(h16x8*)(lA + (i*32+sr)*64 + ssl*8) = ra[i];
        *(h16x8*)(lB + (i*32+sr)*64 + ssl*8) = rb[i];
      }
    }
    __syncthreads();
  }

  // epilogue: RoPE (q,k) + scatter to (b,h,s,d)
  const int proj = nt >> 3;   // 0=q 1=k 2=v (uniform per block)
  h16* dst = proj == 0 ? qh : (proj == 1 ? kh : vh);
  #pragma unroll
  for (int mf = 0; mf < 4; mf++) {
    #pragma unroll
    for (int nf = 0; nf < 4; nf++) {
      #pragma unroll
      for (int r = 0; r < 4; r++) {
        float v = acc[mf][nf][r];
        int row = wr*64 + mf*16 + ((l >> 4) << 2) + r;
        int col = wc*64 + nf*16 + (l & 15);
        int tk = m0 + row;
        int b = tk >> 13;
        int s = tk & 8191;
        int e = (n0 & 1023) + col;
        int hh = e >> 6, d = e & 63;
        if (proj < 2) {
          float2 cs = *(const float2*)(fc + ((size_t)s*32 + (d >> 1))*2);
          float p = __shfl_xor(v, 1);
          v = (d & 1) ? (v*cs.x + p*cs.y) : (v*cs.x - p*cs.y);
        }
        dst[((size_t)((b*16 + hh)*8192 + s) << 6) + d] = (h16)v;
      }
    }
  }
}

// ---------------- transpose: K->(K^T * k_dec), V->V^T  (per bh, per chunk) --
__global__ __launch_bounds__(256) void k_tr(
    const h16* __restrict__ kh, const h16* __restrict__ vh,
    h16* __restrict__ kts, h16* __restrict__ vt)
{
  __shared__ __align__(16) h16 tl[128*64];
  __shared__ float dt[128];
  const int tid = threadIdx.x;
  const int st = blockIdx.x;   // chunk 0..63
  const int bh = blockIdx.y;   // 0..31
  const int h = bh & 15;
  if (tid < 128) {
    float slope = exp2f(-0.5f * (float)(h + 1));
    dt[tid] = expf(-slope * (float)(127 - tid));
  }
  const size_t ibase = ((size_t)bh*8192 + st*128) * 64;
  const size_t obase = (size_t)bh*64*8192 + st*128;
  const int cr = tid >> 3, c8 = tid & 7;

  for (int which = 0; which < 2; ++which) {
    const h16* src = which ? vh : kh;
    h16* dstp = which ? vt : kts;
    __syncthreads();
    #pragma unroll
    for (int i = 0; i < 4; i++) {
      int r = i*32 + cr;
      h16x8 v = *(const h16x8*)(src + ibase + (size_t)r*64 + c8*8);
      int slot = (c8 + ((r >> 3) & 7)) & 7;     // rotate to spread banks
      *(h16x8*)(tl + r*64 + slot*8) = v;
    }
    __syncthreads();
    #pragma unroll
    for (int i = 0; i < 4; i++) {
      int chunk = i*256 + tid;
      int d = chunk >> 4;       // 0..63
      int j8 = chunk & 15;      // 0..15
      h16x8 o;
      #pragma unroll
      for (int jj = 0; jj < 8; jj++) {
        int c = j8*8 + jj;
        int pos = (d + ((c >> 3) & 7)*8) & 63;
        float fv = (float)tl[c*64 + pos];
        if (!which) fv *= dt[c];
        o[jj] = (h16)fv;
      }
      *(h16x8*)(dstp + obase + (size_t)d*8192 + j8*8) = o;
    }
  }
}

// ---------------- per-chunk KV^T state: T[e][d] = sum_c V^T[e][c]*K_s^T[d][c]
__global__ __launch_bounds__(256) void k_kv(
    const h16* __restrict__ kts, const h16* __restrict__ vt,
    float* __restrict__ T)
{
  const int tid = threadIdx.x;
  const int t = blockIdx.x;    // chunk
  const int bh = blockIdx.y;
  const int w = tid >> 6, l = tid & 63;
  const h16* vb = vt  + (size_t)bh*64*8192 + t*128;
  const h16* kb = kts + (size_t)bh*64*8192 + t*128;
  f32x4 acc[4] = {};
  h16x8 a[4];
  #pragma unroll
  for (int ks = 0; ks < 4; ks++)
    a[ks] = *(const h16x8*)(vb + (size_t)(w*16 + (l & 15))*8192 + ks*32 + (l >> 4)*8);
  #pragma unroll
  for (int nf = 0; nf < 4; nf++) {
    #pragma unroll
    for (int ks = 0; ks < 4; ks++) {
      h16x8 bfr = *(const h16x8*)(kb + (size_t)(nf*16 + (l & 15))*8192 + ks*32 + (l >> 4)*8);
      acc[nf] = MFMA16(a[ks], bfr, acc[nf]);
    }
  }
  float* Tb = T + ((size_t)bh*64 + t)*4096;
  #pragma unroll
  for (int nf = 0; nf < 4; nf++)
    #pragma unroll
    for (int r = 0; r < 4; r++) {
      int e = w*16 + ((l >> 4) << 2) + r;
      int d = nf*16 + (l & 15);
      Tb[e*64 + d] = acc[nf][r];
    }
}

// ---------------- decay prefix scan over chunks (in-register state) --------
__global__ __launch_bounds__(256) void k_scan(const float* __restrict__ T,
                                              h16* __restrict__ ph) {
  const int tid = threadIdx.x;
  const int bh = blockIdx.x;
  const int h = bh & 15;
  const float cdec = expf(-exp2f(-0.5f*(float)(h+1)) * 128.0f);
  float run[16];
  #pragma unroll
  for (int j = 0; j < 16; j++) run[j] = 0.f;
  const float* Tb = T + (size_t)bh*64*4096;
  h16* pb = ph + (size_t)bh*64*4096;
  for (int t = 0; t < 64; t++) {
    #pragma unroll
    for (int j = 0; j < 16; j++) {
      int idx = t*4096 + j*256 + tid;
      float kv = Tb[idx];
      pb[idx] = (h16)run[j];            // state BEFORE this chunk
      run[j] = cdec*run[j] + kv;
    }
  }
}

// ---------------- per-chunk attention output ------------------------------
__global__ __launch_bounds__(256) void k_att(
    const h16* __restrict__ qh, const h16* __restrict__ kh,
    const h16* __restrict__ vt, const h16* __restrict__ ph,
    float* __restrict__ out)
{
  __shared__ __align__(16) h16 P[128*144];   // padded stride 144 halves
  __shared__ float dt[128], qd[128];
  const int tid = threadIdx.x;
  const int t = blockIdx.x;
  const int bh = blockIdx.y;
  const int b = bh >> 4, h = bh & 15;
  if (tid < 128) {
    float slope = exp2f(-0.5f*(float)(h+1));
    dt[tid] = expf(-slope*(float)tid);
    qd[tid] = expf(-slope*(float)(tid+1));
  }
  __syncthreads();
  const int w = tid >> 6, l = tid & 63;
  const int iw = w * 32;
  const h16* qb = qh + ((size_t)bh*8192 + t*128)*64;
  const h16* kb = kh + ((size_t)bh*8192 + t*128)*64;
  const h16* vb = vt + (size_t)bh*64*8192 + t*128;
  const h16* pb = ph + ((size_t)bh*64 + t)*4096;

  h16x8 aq[2][2];
  #pragma unroll
  for (int mf = 0; mf < 2; mf++)
    #pragma unroll
    for (int ks = 0; ks < 2; ks++)
      aq[mf][ks] = *(const h16x8*)(qb + (size_t)(iw + mf*16 + (l & 15))*64 + ks*32 + (l >> 4)*8);

  // QK^T
  f32x4 sc[2][8] = {};
  #pragma unroll
  for (int nf = 0; nf < 8; nf++) {
    #pragma unroll
    for (int ks = 0; ks < 2; ks++) {
      h16x8 bk = *(const h16x8*)(kb + (size_t)(nf*16 + (l & 15))*64 + ks*32 + (l >> 4)*8);
      sc[0][nf] = MFMA16(aq[0][ks], bk, sc[0][nf]);
      sc[1][nf] = MFMA16(aq[1][ks], bk, sc[1][nf]);
    }
  }
  // decay mask + P to LDS (wave-private rows -> no barrier needed)
  #pragma unroll
  for (int mf = 0; mf < 2; mf++) {
    #pragma unroll
    for (int nf = 0; nf < 8; nf++) {
      #pragma unroll
      for (int r = 0; r < 4; r++) {
        int i = iw + mf*16 + ((l >> 4) << 2) + r;
        int j = nf*16 + (l & 15);
        int diff = i - j;
        float v = diff >= 0 ? sc[mf][nf][r]*dt[diff] : 0.f;
        P[i*144 + j] = (h16)v;
      }
    }
  }
  // P @ V
  f32x4 ao[2][4] = {};
  #pragma unroll
  for (int kc = 0; kc < 4; kc++) {
    h16x8 ap0 = *(const h16x8*)(P + (size_t)(iw + (l & 15))*144 + kc*32 + (l >> 4)*8);
    h16x8 ap1 = *(const h16x8*)(P + (size_t)(iw + 16 + (l & 15))*144 + kc*32 + (l >> 4)*8);
    #pragma unroll
    for (int nf = 0; nf < 4; nf++) {
      h16x8 bv = *(const h16x8*)(vb + (size_t)(nf*16 + (l & 15))*8192 + kc*32 + (l >> 4)*8);
      ao[0][nf] = MFMA16(ap0, bv, ao[0][nf]);
      ao[1][nf] = MFMA16(ap1, bv, ao[1][nf]);
    }
  }
  // Q @ S_prefix
  f32x4 a2[2][4] = {};
  #pragma unroll
  for (int ks = 0; ks < 2; ks++) {
    #pragma unroll
    for (int nf = 0; nf < 4; nf++) {
      h16x8 bs = *(const h16x8*)(pb + (size_t)(nf*16 + (l & 15))*64 + ks*32 + (l >> 4)*8);
      a2[0][nf] = MFMA16(aq[0][ks], bs, a2[0][nf]);
      a2[1][nf] = MFMA16(aq[1][ks], bs, a2[1][nf]);
    }
  }
  // epilogue -> O (b,s,E) fp32 in d_out
  #pragma unroll
  for (int mf = 0; mf < 2; mf++) {
    #pragma unroll
    for (int nf = 0; nf < 4; nf++) {
      #pragma unroll
      for (int r = 0; r < 4; r++) {
        int i = iw + mf*16 + ((l >> 4) << 2) + r;
        int e = nf*16 + (l & 15);
        float o = ao[mf][nf][r] + qd[i]*a2[mf][nf][r];
        int s = t*128 + i;
        out[((size_t)(b*8192 + s))*1024 + h*64 + e] = o;
      }
    }
  }
}

// ---------------- RMSNorm (per token) -> fp16 -----------------------------
__global__ __launch_bounds__(256) void k_rms(const float* __restrict__ o,
                                             const float* __restrict__ rw,
                                             h16* __restrict__ an) {
  const int tid = threadIdx.x;
  const size_t base = (size_t)blockIdx.x * 1024;
  float4 v = *(const float4*)(o + base + tid*4);
  float ss = v.x*v.x + v.y*v.y + v.z*v.z + v.w*v.w;
  #pragma unroll
  for (int off = 32; off > 0; off >>= 1) ss += __shfl_down(ss, off);
  __shared__ float red[4];
  if ((tid & 63) == 0) red[tid >> 6] = ss;
  __syncthreads();
  float f = rsqrtf((red[0]+red[1]+red[2]+red[3]) * (1.0f/1024.0f) + 1e-5f);
  float4 wv = *(const float4*)(rw + tid*4);
  h16x4 r;
  r[0] = (h16)(v.x*f*wv.x); r[1] = (h16)(v.y*f*wv.y);
  r[2] = (h16)(v.z*f*wv.z); r[3] = (h16)(v.w*f*wv.w);
  *(h16x4*)(an + base + tid*4) = r;
}

// ---------------- final GEMM: out = An @ wo^T (M=16384, N=1024, K=1024) ---
__global__ __launch_bounds__(256) void k_out(
    const h16* __restrict__ an, const h16* __restrict__ woh,
    float* __restrict__ out)
{
  __shared__ __align__(16) h16 lA[128*64];
  __shared__ __align__(16) h16 lB[128*64];
  const int tid = threadIdx.x;
  const int m0 = blockIdx.x * 128;
  const int n0 = blockIdx.y * 128;
  const int w = tid >> 6, l = tid & 63;
  const int wr = w >> 1, wc = w & 1;
  const int sr = tid >> 3, sc = tid & 7;
  const int ssl = sc ^ (sr & 7);
  const h16* At = an + (size_t)m0 * 1024;
  const h16* Bt = woh + (size_t)n0 * 1024;

  f32x4 acc[4][4] = {};
  h16x8 ra[4], rb[4];
  #pragma unroll
  for (int i = 0; i < 4; i++) {
    ra[i] = *(const h16x8*)(At + (size_t)(i*32+sr)*1024 + sc*8);
    rb[i] = *(const h16x8*)(Bt + (size_t)(i*32+sr)*1024 + sc*8);
  }
  #pragma unroll
  for (int i = 0; i < 4; i++) {
    *(h16x8*)(lA + (i*32+sr)*64 + ssl*8) = ra[i];
    *(h16x8*)(lB + (i*32+sr)*64 + ssl*8) = rb[i];
  }
  __syncthreads();

  for (int kt = 0; kt < 16; ++kt) {
    if (kt < 15) {
      #pragma unroll
      for (int i = 0; i < 4; i++) {
        ra[i] = *(const h16x8*)(At + (size_t)(i*32+sr)*1024 + (kt+1)*64 + sc*8);
        rb[i] = *(const h16x8*)(Bt + (size_t)(i*32+sr)*1024 + (kt+1)*64 + sc*8);
      }
    }
    #pragma unroll
    for (int ks = 0; ks < 2; ++ks) {
      h16x8 af[4], bf[4];
      #pragma unroll
      for (int mf = 0; mf < 4; mf++) {
        int row = wr*64 + mf*16 + (l & 15);
        int slot = (ks*4 + (l >> 4)) ^ (row & 7);
        af[mf] = *(const h16x8*)(lA + row*64 + slot*8);
      }
      #pragma unroll
      for (int nf = 0; nf < 4; nf++) {
        int row = wc*64 + nf*16 + (l & 15);
        int slot = (ks*4 + (l >> 4)) ^ (row & 7);
        bf[nf] = *(const h16x8*)(lB + row*64 + slot*8);
      }
      #pragma unroll
      for (int mf = 0; mf < 4; mf++)
        #pragma unroll
        for (int nf = 0; nf < 4; nf++)
          acc[mf][nf] = MFMA16(af[mf], bf[nf], acc[mf][nf]);
    }
    __syncthreads();
    if (kt < 15) {
      #pragma unroll
      for (int i = 0; i < 4; i++) {
        *(h16x8*)(lA + (i*32+sr)*64 + ssl*8) = ra[i];
        *(h16x8*)(lB + (i*32+sr)*64 + ssl*8) = rb[i];
      }
    }
    __syncthreads();
  }
  #pragma unroll
  for (int mf = 0; mf < 4; mf++)
    #pragma unroll
    for (int nf = 0; nf < 4; nf++)
      #pragma unroll
      for (int r = 0; r < 4; r++) {
        int row = wr*64 + mf*16 + ((l >> 4) << 2) + r;
        int col = wc*64 + nf*16 + (l & 15);
        out[(size_t)(m0 + row)*1024 + n0 + col] = acc[mf][nf][r];
      }
}

// --------------------------------------------------------------------------
extern "C" void kernel_launch(void* const* d_in, const int* in_sizes, int n_in,
                              void* d_out, int out_size, void* d_ws, size_t ws_size,
                              hipStream_t stream) {
  const float* x  = (const float*)d_in[0];
  const float* fc = (const float*)d_in[1];
  const float* wq = (const float*)d_in[2];
  const float* wk = (const float*)d_in[3];
  const float* wv = (const float*)d_in[4];
  const float* wo = (const float*)d_in[5];
  const float* rw = (const float*)d_in[6];
  float* out = (float*)d_out;

  char* p = (char*)d_ws;
  const size_t SZ = 33554432;            // 16.8M halves
  h16* xh  = (h16*)(p);                  // later reused for An
  h16* qh  = (h16*)(p + SZ);
  h16* kh  = (h16*)(p + 2*SZ);
  h16* vh  = (h16*)(p + 3*SZ);           // later reused for Ph
  h16* kts = (h16*)(p + 4*SZ);
  h16* vt  = (h16*)(p + 5*SZ);
  float* T = (float*)(p + 6*SZ);
  h16* w3  = (h16*)(p + 7*SZ);           // wq|wk|wv fp16 (6 MB)
  h16* woh = (h16*)(p + 7*SZ + 6291456); // 2 MB

  hipLaunchKernelGGL(k_cvt, dim3(8192), dim3(256), 0, stream, x, xh, 16777216);
  hipLaunchKernelGGL(k_cvt, dim3(512), dim3(256), 0, stream, wq, w3, 1048576);
  hipLaunchKernelGGL(k_cvt, dim3(512), dim3(256), 0, stream, wk, w3 + 1048576, 1048576);
  hipLaunchKernelGGL(k_cvt, dim3(512), dim3(256), 0, stream, wv, w3 + 2097152, 1048576);
  hipLaunchKernelGGL(k_cvt, dim3(512), dim3(256), 0, stream, wo, woh, 1048576);

  hipLaunchKernelGGL(k_qkv, dim3(128, 24), dim3(256), 0, stream, xh, w3, fc, qh, kh, vh);
  hipLaunchKernelGGL(k_tr,  dim3(64, 32), dim3(256), 0, stream, kh, vh, kts, vt);
  hipLaunchKernelGGL(k_kv,  dim3(64, 32), dim3(256), 0, stream, kts, vt, T);
  h16* ph = vh;  // vh dead after k_tr
  hipLaunchKernelGGL(k_scan, dim3(32), dim3(256), 0, stream, T, ph);
  hipLaunchKernelGGL(k_att, dim3(64, 32), dim3(256), 0, stream, qh, kh, vt, ph, out);
  h16* an = xh;  // xh dead after k_qkv
  hipLaunchKernelGGL(k_rms, dim3(16384), dim3(256), 0, stream, out, rw, an);
  hipLaunchKernelGGL(k_out, dim3(128, 8), dim3(256), 0, stream, an, woh, out);
}